// Round 1
// baseline (1963.258 us; speedup 1.0000x reference)
//
#include <hip/hip_runtime.h>

// ChunkwiseDeltaAttention (MI355X/gfx950)
// B=4 L=4096 H=2048 NH=16 D=128 C=64 -> M=16384, K=N=2048
//
// Pipeline:
//   beta_kernel: beta = softplus(hs @ b_w^T + b_b)           [M,16] f32
//   gemm_bt<0>:  q  = hs @ q_w^T + q_b                        bf16 -> ws.qy
//   gemm_bt<0>:  k  = hs @ k_w^T + k_b                        bf16 -> ws.kn
//   gemm_bt<1>:  gv = beta * (hs @ v_w^T + v_b)               bf16 -> ws.gv
//   gemm_bt<2>:  gate = silu(hs @ og_w^T)                     bf16 -> ws.gate
//   attn_kernel: per (chunk,head): l2norm(q),l2norm(k) in LDS,
//                S = q k^T (MFMA), causal mask (mask==lower-tri ones:
//                exp(-0.1*clip(j-i,0)) with j<=i is exp(0)=1),
//                O = S gv (MFMA), y = O*gate  -> overwrites ws.qy (same
//                region this block staged from; safe per-block)
//   gemm_bt<3>:  out = y @ o_w^T + o_b                        f32 -> d_out
//
// Scratch layout (d_ws): qy 64MB | kn 64MB | gv 64MB | gate 64MB | beta 1MB
//   total ~270MB, fully initialized before reads (ws poisoned 0xAA).

typedef __bf16 bf16x8 __attribute__((ext_vector_type(8)));
typedef float f32x4 __attribute__((ext_vector_type(4)));

__device__ __forceinline__ unsigned short f2bf(float x) {
  unsigned u = __builtin_bit_cast(unsigned, x);
  u += 0x7fffu + ((u >> 16) & 1u);          // RNE
  return (unsigned short)(u >> 16);
}
__device__ __forceinline__ float bf2f(unsigned short h) {
  return __builtin_bit_cast(float, (unsigned)h << 16);
}
__device__ __forceinline__ unsigned pk2(float a, float b) {
  return (unsigned)f2bf(a) | ((unsigned)f2bf(b) << 16);
}

// ---------------------------------------------------------------- beta ----
__global__ __launch_bounds__(256) void beta_kernel(
    const float* __restrict__ hs, const float* __restrict__ bw,
    const float* __restrict__ bb, float* __restrict__ beta) {
  __shared__ float row[2048];
  __shared__ float part[16][17];
  const int m = blockIdx.x;
  const float* src = hs + (size_t)m * 2048;
  for (int i = threadIdx.x; i < 512; i += 256)
    ((float4*)row)[i] = ((const float4*)src)[i];
  __syncthreads();
  const int h = threadIdx.x >> 4, j = threadIdx.x & 15;
  const float* w = bw + h * 2048;
  float s = 0.f;
  #pragma unroll 8
  for (int kk = 0; kk < 128; kk++) {
    int k = j + (kk << 4);                  // lane-interleaved: LDS conflict-free
    s += row[k] * w[k];
  }
  part[h][j] = s;
  __syncthreads();
  if (threadIdx.x < 16) {
    int hh = threadIdx.x;
    float t = bb[hh];
    #pragma unroll
    for (int j2 = 0; j2 < 16; j2++) t += part[hh][j2];
    float sp = fmaxf(t, 0.f) + log1pf(__expf(-fabsf(t)));   // stable softplus
    beta[(size_t)m * 16 + hh] = sp;
  }
}

// ---------------------------------------------------------------- GEMM ----
// C[m,n] = sum_k A[m,k]*B[n,k]  (+epilogue). A: f32 or bf16; B: f32 weights.
// Tile 128x128, BK=32, 4 waves in 2x2, each wave 4x4 of 16x16x32 bf16 MFMA.
// EPI: 0 = +bias, bf16 out | 1 = (+bias)*beta[row,head], bf16 out
//      2 = silu, bf16 out  | 3 = +bias, f32 out
constexpr int GLDW = 40;   // LDS row stride (bf16 elems), 32 + 8 pad

template <int EPI, bool ABF16>
__global__ __launch_bounds__(256) void gemm_bt(
    const void* __restrict__ Av, const float* __restrict__ Bw,
    const float* __restrict__ bias, const float* __restrict__ beta,
    void* __restrict__ Cv, int M, int N, int K) {
  __shared__ unsigned short As[128 * GLDW];
  __shared__ unsigned short Bs[128 * GLDW];
  const int tid = threadIdx.x;
  const int m0 = blockIdx.y * 128;
  const int n0 = blockIdx.x * 128;
  const int wid = tid >> 6, lane = tid & 63;
  const int wm = wid >> 1, wn = wid & 1;
  const int quad = lane >> 4, l16 = lane & 15;
  const int srow = tid >> 1, skh = (tid & 1) << 4;   // each thread stages 16 elems

  f32x4 acc[4][4] = {};

  const float* Bg = Bw + (size_t)(n0 + srow) * K + skh;

  for (int kb = 0; kb < K; kb += 32) {
    if (ABF16) {
      const unsigned short* Ag =
          (const unsigned short*)Av + (size_t)(m0 + srow) * K + kb + skh;
      uint4 u0 = ((const uint4*)Ag)[0];
      uint4 u1 = ((const uint4*)Ag)[1];
      uint4* d = (uint4*)&As[srow * GLDW + skh];
      d[0] = u0; d[1] = u1;
    } else {
      const float* Ag = (const float*)Av + (size_t)(m0 + srow) * K + kb + skh;
      float4 f0 = ((const float4*)Ag)[0];
      float4 f1 = ((const float4*)Ag)[1];
      float4 f2 = ((const float4*)Ag)[2];
      float4 f3 = ((const float4*)Ag)[3];
      unsigned* d = (unsigned*)&As[srow * GLDW + skh];
      d[0] = pk2(f0.x, f0.y); d[1] = pk2(f0.z, f0.w);
      d[2] = pk2(f1.x, f1.y); d[3] = pk2(f1.z, f1.w);
      d[4] = pk2(f2.x, f2.y); d[5] = pk2(f2.z, f2.w);
      d[6] = pk2(f3.x, f3.y); d[7] = pk2(f3.z, f3.w);
    }
    {
      const float* Bgk = Bg + kb;
      float4 f0 = ((const float4*)Bgk)[0];
      float4 f1 = ((const float4*)Bgk)[1];
      float4 f2 = ((const float4*)Bgk)[2];
      float4 f3 = ((const float4*)Bgk)[3];
      unsigned* d = (unsigned*)&Bs[srow * GLDW + skh];
      d[0] = pk2(f0.x, f0.y); d[1] = pk2(f0.z, f0.w);
      d[2] = pk2(f1.x, f1.y); d[3] = pk2(f1.z, f1.w);
      d[4] = pk2(f2.x, f2.y); d[5] = pk2(f2.z, f2.w);
      d[6] = pk2(f3.x, f3.y); d[7] = pk2(f3.z, f3.w);
    }
    __syncthreads();
    bf16x8 af[4], bfr[4];
    #pragma unroll
    for (int mi = 0; mi < 4; mi++)
      af[mi] = *(const bf16x8*)&As[(wm * 64 + mi * 16 + l16) * GLDW + (quad << 3)];
    #pragma unroll
    for (int ni = 0; ni < 4; ni++)
      bfr[ni] = *(const bf16x8*)&Bs[(wn * 64 + ni * 16 + l16) * GLDW + (quad << 3)];
    #pragma unroll
    for (int mi = 0; mi < 4; mi++)
      #pragma unroll
      for (int ni = 0; ni < 4; ni++)
        acc[mi][ni] = __builtin_amdgcn_mfma_f32_16x16x32_bf16(
            af[mi], bfr[ni], acc[mi][ni], 0, 0, 0);
    __syncthreads();
  }

  // epilogue; C/D layout: col=lane&15, row=quad*4+reg (verified m89/m91)
  #pragma unroll
  for (int mi = 0; mi < 4; mi++) {
    #pragma unroll
    for (int r = 0; r < 4; r++) {
      const int row = m0 + wm * 64 + mi * 16 + quad * 4 + r;
      float bsc = 1.f;
      if (EPI == 1) bsc = beta[(size_t)row * 16 + blockIdx.x];  // BN=128 == head width
      #pragma unroll
      for (int ni = 0; ni < 4; ni++) {
        const int col = n0 + wn * 64 + ni * 16 + l16;
        float x = acc[mi][ni][r];
        if (EPI != 2) x += bias[col];
        if (EPI == 1) x *= bsc;
        if (EPI == 2) x = x / (1.f + __expf(-x));   // silu
        if (EPI == 3)
          ((float*)Cv)[(size_t)row * N + col] = x;
        else
          ((unsigned short*)Cv)[(size_t)row * N + col] = f2bf(x);
      }
    }
  }
}

// ----------------------------------------------------------- attention ----
// One block per (chunk cid 0..255, head h 0..15). Rows m0=cid*64.
// Stages q,k (row-major, padded) + gv (transposed) in LDS; normalizes q,k
// in LDS; S=q k^T via MFMA; causal mask (ones); S->bf16 LDS; O=S gv via
// MFMA; y = O*gate overwrites the q buffer.
constexpr int QK_LDW = 136;  // 128 + 8 pad (bf16 elems)
constexpr int GT_LDW = 72;   // 64 + 8 pad
constexpr int SS_LDW = 72;

__global__ __launch_bounds__(256) void attn_kernel(
    const unsigned short* __restrict__ qn, const unsigned short* __restrict__ kn,
    const unsigned short* __restrict__ gvp, const unsigned short* __restrict__ gate,
    unsigned short* __restrict__ y) {
  __shared__ unsigned short qs[64 * QK_LDW];
  __shared__ unsigned short ks[64 * QK_LDW];
  __shared__ unsigned short gst[128 * GT_LDW];   // gst[d][j] = gv[j][d]
  __shared__ unsigned short Ss[64 * SS_LDW];

  const int tid = threadIdx.x;
  const int m0 = blockIdx.x * 64;
  const int h = blockIdx.y;
  const size_t gbase = (size_t)m0 * 2048 + (size_t)h * 128;

  // ---- stage
  #pragma unroll
  for (int it = 0; it < 4; it++) {
    int e = tid + it * 256;          // 0..1023
    int i = e >> 4;                  // row 0..63
    int c = (e & 15) << 3;           // col 0..120
    size_t g = gbase + (size_t)i * 2048 + c;
    *(uint4*)&qs[i * QK_LDW + c] = *(const uint4*)&qn[g];
    *(uint4*)&ks[i * QK_LDW + c] = *(const uint4*)&kn[g];
    uint4 gvv = *(const uint4*)&gvp[g];
    unsigned short tmp[8];
    *(uint4*)tmp = gvv;
    #pragma unroll
    for (int t = 0; t < 8; t++) gst[(c + t) * GT_LDW + i] = tmp[t];
  }
  __syncthreads();

  // ---- l2 normalize q,k rows in LDS (4 threads per row)
  {
    const int rr = tid >> 2;
    const int seg = (tid & 3) * 32;
    float ssq = 0.f, ssk = 0.f;
    #pragma unroll
    for (int k2 = 0; k2 < 32; k2 += 2) {
      unsigned uq = *(const unsigned*)&qs[rr * QK_LDW + seg + k2];
      unsigned uk = *(const unsigned*)&ks[rr * QK_LDW + seg + k2];
      float a = bf2f((unsigned short)(uq & 0xffff)), b = bf2f((unsigned short)(uq >> 16));
      float c2 = bf2f((unsigned short)(uk & 0xffff)), d2 = bf2f((unsigned short)(uk >> 16));
      ssq += a * a + b * b;
      ssk += c2 * c2 + d2 * d2;
    }
    ssq += __shfl_xor(ssq, 1); ssq += __shfl_xor(ssq, 2);
    ssk += __shfl_xor(ssk, 1); ssk += __shfl_xor(ssk, 2);
    float iq = rsqrtf(fmaxf(ssq, 1e-24f));
    float ik = rsqrtf(fmaxf(ssk, 1e-24f));
    #pragma unroll
    for (int k2 = 0; k2 < 32; k2 += 2) {
      unsigned uq = *(const unsigned*)&qs[rr * QK_LDW + seg + k2];
      unsigned uk = *(const unsigned*)&ks[rr * QK_LDW + seg + k2];
      float a = bf2f((unsigned short)(uq & 0xffff)), b = bf2f((unsigned short)(uq >> 16));
      float c2 = bf2f((unsigned short)(uk & 0xffff)), d2 = bf2f((unsigned short)(uk >> 16));
      *(unsigned*)&qs[rr * QK_LDW + seg + k2] = pk2(a * iq, b * iq);
      *(unsigned*)&ks[rr * QK_LDW + seg + k2] = pk2(c2 * ik, d2 * ik);
    }
  }
  __syncthreads();

  const int w = tid >> 6;
  const int lane = tid & 63;
  const int quad = lane >> 4, l16 = lane & 15;

  // ---- S = q k^T for rows [16w,16w+16), mask, to bf16 LDS
  {
    f32x4 acc[4] = {};
    #pragma unroll
    for (int kst = 0; kst < 4; kst++) {
      bf16x8 a = *(const bf16x8*)&qs[(w * 16 + l16) * QK_LDW + kst * 32 + (quad << 3)];
      #pragma unroll
      for (int ni = 0; ni < 4; ni++) {
        bf16x8 b = *(const bf16x8*)&ks[(ni * 16 + l16) * QK_LDW + kst * 32 + (quad << 3)];
        acc[ni] = __builtin_amdgcn_mfma_f32_16x16x32_bf16(a, b, acc[ni], 0, 0, 0);
      }
    }
    #pragma unroll
    for (int ni = 0; ni < 4; ni++)
      #pragma unroll
      for (int r = 0; r < 4; r++) {
        int row = w * 16 + quad * 4 + r;
        int col = ni * 16 + l16;
        float val = (col <= row) ? acc[ni][r] : 0.f;  // decay==1 inside causal region
        Ss[row * SS_LDW + col] = f2bf(val);
      }
  }
  __syncthreads();

  // ---- O = S gv, y = O * gate
  {
    f32x4 acc[8] = {};
    #pragma unroll
    for (int kst = 0; kst < 2; kst++) {
      bf16x8 a = *(const bf16x8*)&Ss[(w * 16 + l16) * SS_LDW + kst * 32 + (quad << 3)];
      #pragma unroll
      for (int nd = 0; nd < 8; nd++) {
        bf16x8 b = *(const bf16x8*)&gst[(nd * 16 + l16) * GT_LDW + kst * 32 + (quad << 3)];
        acc[nd] = __builtin_amdgcn_mfma_f32_16x16x32_bf16(a, b, acc[nd], 0, 0, 0);
      }
    }
    #pragma unroll
    for (int nd = 0; nd < 8; nd++)
      #pragma unroll
      for (int r = 0; r < 4; r++) {
        int row = w * 16 + quad * 4 + r;
        int col = nd * 16 + l16;
        size_t g = gbase + (size_t)row * 2048 + col;
        float gt = bf2f(gate[g]);
        y[g] = f2bf(acc[nd][r] * gt);
      }
  }
}

// --------------------------------------------------------------- launch ---
extern "C" void kernel_launch(void* const* d_in, const int* in_sizes, int n_in,
                              void* d_out, int out_size, void* d_ws, size_t ws_size,
                              hipStream_t stream) {
  const float* hs   = (const float*)d_in[0];
  const float* q_w  = (const float*)d_in[1];
  const float* q_b  = (const float*)d_in[2];
  const float* k_w  = (const float*)d_in[3];
  const float* k_b  = (const float*)d_in[4];
  const float* v_w  = (const float*)d_in[5];
  const float* v_b  = (const float*)d_in[6];
  // d_in[7]=a_w, d_in[8]=a_b : dead code in reference
  const float* b_w  = (const float*)d_in[9];
  const float* b_b  = (const float*)d_in[10];
  const float* og_w = (const float*)d_in[11];
  const float* o_w  = (const float*)d_in[12];
  const float* o_b  = (const float*)d_in[13];

  const int M = 16384, N = 2048, K = 2048;

  char* ws = (char*)d_ws;
  unsigned short* qy   = (unsigned short*)(ws);                    // 67108864 B
  unsigned short* knb  = (unsigned short*)(ws + 67108864);         // 67108864 B
  unsigned short* gv   = (unsigned short*)(ws + 134217728);        // 67108864 B
  unsigned short* gate = (unsigned short*)(ws + 201326592);        // 67108864 B
  float*          beta = (float*)(ws + 268435456);                 //  1048576 B

  beta_kernel<<<M, 256, 0, stream>>>(hs, b_w, b_b, beta);

  dim3 gg(N / 128, M / 128);
  gemm_bt<0, false><<<gg, 256, 0, stream>>>(hs, q_w, q_b, nullptr, qy, M, N, K);
  gemm_bt<0, false><<<gg, 256, 0, stream>>>(hs, k_w, k_b, nullptr, knb, M, N, K);
  gemm_bt<1, false><<<gg, 256, 0, stream>>>(hs, v_w, v_b, beta, gv, M, N, K);
  gemm_bt<2, false><<<gg, 256, 0, stream>>>(hs, og_w, nullptr, nullptr, gate, M, N, K);

  attn_kernel<<<dim3(256, 16), 256, 0, stream>>>(qy, knb, gv, gate, qy);

  gemm_bt<3, true><<<gg, 256, 0, stream>>>(qy, o_w, o_b, nullptr, (float*)d_out, M, N, K);
}

// Round 2
// 1420.298 us; speedup vs baseline: 1.3823x; 1.3823x over previous
//
#include <hip/hip_runtime.h>

// ChunkwiseDeltaAttention (MI355X/gfx950) — round 2
// B=4 L=4096 H=2048 NH=16 D=128 C=64 -> M=16384, K=2048
//
// Fast path (ws >= ~362 MiB):
//   cvt:   hs -> bf16 hsb; {q,k,v,og}_w -> bf16 wcat [8192,2048]; o_w -> owb
//   beta:  softplus(hs @ b_w^T + b_b)                          [M,16] f32
//   gemm_async<0>: [qy|kn|gv|gate] = hsb @ wcat^T (+bias_cat), per-128-col
//                  epilogue: plain / plain / *beta(head) / silu   bf16
//   attn:  per (chunk,head): l2norm(q),l2norm(k) in LDS, S=qk^T (MFMA),
//          causal mask (decay==1 inside mask), O=S gv (MFMA), y=O*gate -> qy
//   gemm_async<3>: out = y @ o_w^T + o_b                        f32 -> d_out
// GEMM: m97 structure — 128x128 tile, BK=32, global_load_lds width=16
//       (no VALU pack), unpadded LDS, 2-barrier K-loop, 16x16x32 bf16 MFMA.
//
// Fallback path (ws < needed): round-1 kernels (f32 pack staging), known-good.

typedef __bf16 bf16x8 __attribute__((ext_vector_type(8)));
typedef float f32x4 __attribute__((ext_vector_type(4)));

typedef __attribute__((address_space(1))) const unsigned int g_u32;
typedef __attribute__((address_space(3))) unsigned int l_u32;

__device__ __forceinline__ void cp16(const unsigned short* g, unsigned short* l) {
  __builtin_amdgcn_global_load_lds((g_u32*)g, (l_u32*)l, 16, 0, 0);
}

__device__ __forceinline__ unsigned short f2bf(float x) {
  unsigned u = __builtin_bit_cast(unsigned, x);
  u += 0x7fffu + ((u >> 16) & 1u);          // RNE
  return (unsigned short)(u >> 16);
}
__device__ __forceinline__ float bf2f(unsigned short h) {
  return __builtin_bit_cast(float, (unsigned)h << 16);
}
__device__ __forceinline__ unsigned pk2(float a, float b) {
  return (unsigned)f2bf(a) | ((unsigned)f2bf(b) << 16);
}

// ------------------------------------------------------------- convert ----
__global__ __launch_bounds__(256) void cvt_bf16(const float* __restrict__ in,
                                                unsigned short* __restrict__ out,
                                                int n) {
  int i = (blockIdx.x * 256 + threadIdx.x) * 8;
  if (i >= n) return;
  float4 f0 = *(const float4*)(in + i);
  float4 f1 = *(const float4*)(in + i + 4);
  uint4 u;
  u.x = pk2(f0.x, f0.y); u.y = pk2(f0.z, f0.w);
  u.z = pk2(f1.x, f1.y); u.w = pk2(f1.z, f1.w);
  *(uint4*)(out + i) = u;
}

__global__ __launch_bounds__(256) void build_bias(
    const float* __restrict__ qb, const float* __restrict__ kb,
    const float* __restrict__ vb, float* __restrict__ bias_cat) {
  int i = blockIdx.x * 256 + threadIdx.x;   // 0..8191
  float v = 0.f;
  if (i < 2048) v = qb[i];
  else if (i < 4096) v = kb[i - 2048];
  else if (i < 6144) v = vb[i - 4096];
  bias_cat[i] = v;
}

// ---------------------------------------------------------------- beta ----
__global__ __launch_bounds__(256) void beta_kernel(
    const float* __restrict__ hs, const float* __restrict__ bw,
    const float* __restrict__ bb, float* __restrict__ beta) {
  __shared__ float row[2048];
  __shared__ float part[16][17];
  const int m = blockIdx.x;
  const float* src = hs + (size_t)m * 2048;
  for (int i = threadIdx.x; i < 512; i += 256)
    ((float4*)row)[i] = ((const float4*)src)[i];
  __syncthreads();
  const int h = threadIdx.x >> 4, j = threadIdx.x & 15;
  const float* w = bw + h * 2048;
  float s = 0.f;
  #pragma unroll 8
  for (int kk = 0; kk < 128; kk++) {
    int k = j + (kk << 4);
    s += row[k] * w[k];
  }
  part[h][j] = s;
  __syncthreads();
  if (threadIdx.x < 16) {
    int hh = threadIdx.x;
    float t = bb[hh];
    #pragma unroll
    for (int j2 = 0; j2 < 16; j2++) t += part[hh][j2];
    beta[(size_t)m * 16 + hh] = fmaxf(t, 0.f) + log1pf(__expf(-fabsf(t)));
  }
}

// ------------------------------------------------- GEMM (async staging) ----
// C[m,n] = sum_k A[m,k]*B[n,k], A,B bf16 [.,K]. 128x128 tile, BK=32,
// global_load_lds x4 staging into unpadded LDS, 4 waves 2x2, 4x4 MFMA accs.
// EPI 0: fused qkvg epilogue — Cv is base of 4 contiguous [M,2048] bf16
//        buffers (q,k,v,gate); n0>>11 selects buffer/mode.
// EPI 3: f32 out [M,N], +bias.
template <int EPI>
__global__ __launch_bounds__(256) void gemm_async(
    const unsigned short* __restrict__ A, const unsigned short* __restrict__ Bw,
    const float* __restrict__ bias, const float* __restrict__ beta,
    void* __restrict__ Cv, int M, int N, int K) {
  __shared__ __align__(16) unsigned short As[128 * 32];
  __shared__ __align__(16) unsigned short Bs[128 * 32];
  const int tid = threadIdx.x;
  const int m0 = blockIdx.y * 128;
  const int n0 = blockIdx.x * 128;
  const int wid = tid >> 6, lane = tid & 63;
  const int wm = wid >> 1, wn = wid & 1;
  const int quad = lane >> 4, l16 = lane & 15;

  // staging: chunk c = r*256+tid -> row c>>2 (0..127), col (c&3)*8
  const int srow = tid >> 2;
  const int scol = (tid & 3) << 3;
  const unsigned short* Ag0 = A + (size_t)(m0 + srow) * K + scol;
  const unsigned short* Ag1 = Ag0 + (size_t)64 * K;
  const unsigned short* Bg0 = Bw + (size_t)(n0 + srow) * K + scol;
  const unsigned short* Bg1 = Bg0 + (size_t)64 * K;
  unsigned short* la0 = &As[tid * 8];
  unsigned short* la1 = &As[(tid + 256) * 8];
  unsigned short* lb0 = &Bs[tid * 8];
  unsigned short* lb1 = &Bs[(tid + 256) * 8];

  f32x4 acc[4][4] = {};

  for (int kb = 0; kb < K; kb += 32) {
    cp16(Ag0 + kb, la0);
    cp16(Ag1 + kb, la1);
    cp16(Bg0 + kb, lb0);
    cp16(Bg1 + kb, lb1);
    __syncthreads();
    bf16x8 af[4], bfr[4];
    #pragma unroll
    for (int mi = 0; mi < 4; mi++)
      af[mi] = *(const bf16x8*)&As[(wm * 64 + mi * 16 + l16) * 32 + (quad << 3)];
    #pragma unroll
    for (int ni = 0; ni < 4; ni++)
      bfr[ni] = *(const bf16x8*)&Bs[(wn * 64 + ni * 16 + l16) * 32 + (quad << 3)];
    #pragma unroll
    for (int mi = 0; mi < 4; mi++)
      #pragma unroll
      for (int ni = 0; ni < 4; ni++)
        acc[mi][ni] = __builtin_amdgcn_mfma_f32_16x16x32_bf16(
            af[mi], bfr[ni], acc[mi][ni], 0, 0, 0);
    __syncthreads();
  }

  // epilogue; C/D layout: col=lane&15, row=quad*4+reg
  if (EPI == 0) {
    const int mode = n0 >> 11;              // 0:q 1:k 2:v 3:gate
    unsigned short* outp =
        (unsigned short*)Cv + (size_t)mode * ((size_t)M * 2048);
    const int head = (n0 >> 7) & 15;
    #pragma unroll
    for (int mi = 0; mi < 4; mi++) {
      #pragma unroll
      for (int r = 0; r < 4; r++) {
        const int row = m0 + wm * 64 + mi * 16 + quad * 4 + r;
        const float bsc = (mode == 2) ? beta[(size_t)row * 16 + head] : 1.f;
        #pragma unroll
        for (int ni = 0; ni < 4; ni++) {
          const int col = n0 + wn * 64 + ni * 16 + l16;
          float x = acc[mi][ni][r] + bias[col];
          if (mode == 2) x *= bsc;
          if (mode == 3) x = x / (1.f + __expf(-x));
          outp[(size_t)row * 2048 + (col & 2047)] = f2bf(x);
        }
      }
    }
  } else {
    #pragma unroll
    for (int mi = 0; mi < 4; mi++)
      #pragma unroll
      for (int r = 0; r < 4; r++) {
        const int row = m0 + wm * 64 + mi * 16 + quad * 4 + r;
        #pragma unroll
        for (int ni = 0; ni < 4; ni++) {
          const int col = n0 + wn * 64 + ni * 16 + l16;
          ((float*)Cv)[(size_t)row * N + col] = acc[mi][ni][r] + bias[col];
        }
      }
  }
}

// --------------------------------------------- fallback GEMM (round 1) ----
constexpr int GLDW = 40;
template <int EPI, bool ABF16>
__global__ __launch_bounds__(256) void gemm_bt(
    const void* __restrict__ Av, const float* __restrict__ Bw,
    const float* __restrict__ bias, const float* __restrict__ beta,
    void* __restrict__ Cv, int M, int N, int K) {
  __shared__ unsigned short As[128 * GLDW];
  __shared__ unsigned short Bs[128 * GLDW];
  const int tid = threadIdx.x;
  const int m0 = blockIdx.y * 128;
  const int n0 = blockIdx.x * 128;
  const int wid = tid >> 6, lane = tid & 63;
  const int wm = wid >> 1, wn = wid & 1;
  const int quad = lane >> 4, l16 = lane & 15;
  const int srow = tid >> 1, skh = (tid & 1) << 4;

  f32x4 acc[4][4] = {};
  const float* Bg = Bw + (size_t)(n0 + srow) * K + skh;

  for (int kb = 0; kb < K; kb += 32) {
    if (ABF16) {
      const unsigned short* Ag =
          (const unsigned short*)Av + (size_t)(m0 + srow) * K + kb + skh;
      uint4 u0 = ((const uint4*)Ag)[0];
      uint4 u1 = ((const uint4*)Ag)[1];
      uint4* d = (uint4*)&As[srow * GLDW + skh];
      d[0] = u0; d[1] = u1;
    } else {
      const float* Ag = (const float*)Av + (size_t)(m0 + srow) * K + kb + skh;
      float4 f0 = ((const float4*)Ag)[0];
      float4 f1 = ((const float4*)Ag)[1];
      float4 f2 = ((const float4*)Ag)[2];
      float4 f3 = ((const float4*)Ag)[3];
      unsigned* d = (unsigned*)&As[srow * GLDW + skh];
      d[0] = pk2(f0.x, f0.y); d[1] = pk2(f0.z, f0.w);
      d[2] = pk2(f1.x, f1.y); d[3] = pk2(f1.z, f1.w);
      d[4] = pk2(f2.x, f2.y); d[5] = pk2(f2.z, f2.w);
      d[6] = pk2(f3.x, f3.y); d[7] = pk2(f3.z, f3.w);
    }
    {
      const float* Bgk = Bg + kb;
      float4 f0 = ((const float4*)Bgk)[0];
      float4 f1 = ((const float4*)Bgk)[1];
      float4 f2 = ((const float4*)Bgk)[2];
      float4 f3 = ((const float4*)Bgk)[3];
      unsigned* d = (unsigned*)&Bs[srow * GLDW + skh];
      d[0] = pk2(f0.x, f0.y); d[1] = pk2(f0.z, f0.w);
      d[2] = pk2(f1.x, f1.y); d[3] = pk2(f1.z, f1.w);
      d[4] = pk2(f2.x, f2.y); d[5] = pk2(f2.z, f2.w);
      d[6] = pk2(f3.x, f3.y); d[7] = pk2(f3.z, f3.w);
    }
    __syncthreads();
    bf16x8 af[4], bfr[4];
    #pragma unroll
    for (int mi = 0; mi < 4; mi++)
      af[mi] = *(const bf16x8*)&As[(wm * 64 + mi * 16 + l16) * GLDW + (quad << 3)];
    #pragma unroll
    for (int ni = 0; ni < 4; ni++)
      bfr[ni] = *(const bf16x8*)&Bs[(wn * 64 + ni * 16 + l16) * GLDW + (quad << 3)];
    #pragma unroll
    for (int mi = 0; mi < 4; mi++)
      #pragma unroll
      for (int ni = 0; ni < 4; ni++)
        acc[mi][ni] = __builtin_amdgcn_mfma_f32_16x16x32_bf16(
            af[mi], bfr[ni], acc[mi][ni], 0, 0, 0);
    __syncthreads();
  }

  #pragma unroll
  for (int mi = 0; mi < 4; mi++) {
    #pragma unroll
    for (int r = 0; r < 4; r++) {
      const int row = m0 + wm * 64 + mi * 16 + quad * 4 + r;
      float bsc = 1.f;
      if (EPI == 1) bsc = beta[(size_t)row * 16 + blockIdx.x];
      #pragma unroll
      for (int ni = 0; ni < 4; ni++) {
        const int col = n0 + wn * 64 + ni * 16 + l16;
        float x = acc[mi][ni][r];
        if (EPI != 2) x += bias[col];
        if (EPI == 1) x *= bsc;
        if (EPI == 2) x = x / (1.f + __expf(-x));
        if (EPI == 3)
          ((float*)Cv)[(size_t)row * N + col] = x;
        else
          ((unsigned short*)Cv)[(size_t)row * N + col] = f2bf(x);
      }
    }
  }
}

// ----------------------------------------------------------- attention ----
constexpr int QK_LDW = 136;
constexpr int GT_LDW = 72;
constexpr int SS_LDW = 72;

__global__ __launch_bounds__(256) void attn_kernel(
    const unsigned short* __restrict__ qn, const unsigned short* __restrict__ kn,
    const unsigned short* __restrict__ gvp, const unsigned short* __restrict__ gate,
    unsigned short* __restrict__ y) {
  __shared__ unsigned short qs[64 * QK_LDW];
  __shared__ unsigned short ks[64 * QK_LDW];
  __shared__ unsigned short gst[128 * GT_LDW];
  __shared__ unsigned short Ss[64 * SS_LDW];

  const int tid = threadIdx.x;
  const int m0 = blockIdx.x * 64;
  const int h = blockIdx.y;
  const size_t gbase = (size_t)m0 * 2048 + (size_t)h * 128;

  #pragma unroll
  for (int it = 0; it < 4; it++) {
    int e = tid + it * 256;
    int i = e >> 4;
    int c = (e & 15) << 3;
    size_t g = gbase + (size_t)i * 2048 + c;
    *(uint4*)&qs[i * QK_LDW + c] = *(const uint4*)&qn[g];
    *(uint4*)&ks[i * QK_LDW + c] = *(const uint4*)&kn[g];
    uint4 gvv = *(const uint4*)&gvp[g];
    unsigned short tmp[8];
    *(uint4*)tmp = gvv;
    #pragma unroll
    for (int t = 0; t < 8; t++) gst[(c + t) * GT_LDW + i] = tmp[t];
  }
  __syncthreads();

  {
    const int rr = tid >> 2;
    const int seg = (tid & 3) * 32;
    float ssq = 0.f, ssk = 0.f;
    #pragma unroll
    for (int k2 = 0; k2 < 32; k2 += 2) {
      unsigned uq = *(const unsigned*)&qs[rr * QK_LDW + seg + k2];
      unsigned uk = *(const unsigned*)&ks[rr * QK_LDW + seg + k2];
      float a = bf2f((unsigned short)(uq & 0xffff)), b = bf2f((unsigned short)(uq >> 16));
      float c2 = bf2f((unsigned short)(uk & 0xffff)), d2 = bf2f((unsigned short)(uk >> 16));
      ssq += a * a + b * b;
      ssk += c2 * c2 + d2 * d2;
    }
    ssq += __shfl_xor(ssq, 1); ssq += __shfl_xor(ssq, 2);
    ssk += __shfl_xor(ssk, 1); ssk += __shfl_xor(ssk, 2);
    float iq = rsqrtf(fmaxf(ssq, 1e-24f));
    float ik = rsqrtf(fmaxf(ssk, 1e-24f));
    #pragma unroll
    for (int k2 = 0; k2 < 32; k2 += 2) {
      unsigned uq = *(const unsigned*)&qs[rr * QK_LDW + seg + k2];
      unsigned uk = *(const unsigned*)&ks[rr * QK_LDW + seg + k2];
      float a = bf2f((unsigned short)(uq & 0xffff)), b = bf2f((unsigned short)(uq >> 16));
      float c2 = bf2f((unsigned short)(uk & 0xffff)), d2 = bf2f((unsigned short)(uk >> 16));
      *(unsigned*)&qs[rr * QK_LDW + seg + k2] = pk2(a * iq, b * iq);
      *(unsigned*)&ks[rr * QK_LDW + seg + k2] = pk2(c2 * ik, d2 * ik);
    }
  }
  __syncthreads();

  const int w = tid >> 6;
  const int lane = tid & 63;
  const int quad = lane >> 4, l16 = lane & 15;

  {
    f32x4 acc[4] = {};
    #pragma unroll
    for (int kst = 0; kst < 4; kst++) {
      bf16x8 a = *(const bf16x8*)&qs[(w * 16 + l16) * QK_LDW + kst * 32 + (quad << 3)];
      #pragma unroll
      for (int ni = 0; ni < 4; ni++) {
        bf16x8 b = *(const bf16x8*)&ks[(ni * 16 + l16) * QK_LDW + kst * 32 + (quad << 3)];
        acc[ni] = __builtin_amdgcn_mfma_f32_16x16x32_bf16(a, b, acc[ni], 0, 0, 0);
      }
    }
    #pragma unroll
    for (int ni = 0; ni < 4; ni++)
      #pragma unroll
      for (int r = 0; r < 4; r++) {
        int row = w * 16 + quad * 4 + r;
        int col = ni * 16 + l16;
        float val = (col <= row) ? acc[ni][r] : 0.f;
        Ss[row * SS_LDW + col] = f2bf(val);
      }
  }
  __syncthreads();

  {
    f32x4 acc[8] = {};
    #pragma unroll
    for (int kst = 0; kst < 2; kst++) {
      bf16x8 a = *(const bf16x8*)&Ss[(w * 16 + l16) * SS_LDW + kst * 32 + (quad << 3)];
      #pragma unroll
      for (int nd = 0; nd < 8; nd++) {
        bf16x8 b = *(const bf16x8*)&gst[(nd * 16 + l16) * GT_LDW + kst * 32 + (quad << 3)];
        acc[nd] = __builtin_amdgcn_mfma_f32_16x16x32_bf16(a, b, acc[nd], 0, 0, 0);
      }
    }
    #pragma unroll
    for (int nd = 0; nd < 8; nd++)
      #pragma unroll
      for (int r = 0; r < 4; r++) {
        int row = w * 16 + quad * 4 + r;
        int col = nd * 16 + l16;
        size_t g = gbase + (size_t)row * 2048 + col;
        float gt = bf2f(gate[g]);
        y[g] = f2bf(acc[nd][r] * gt);
      }
  }
}

// --------------------------------------------------------------- launch ---
extern "C" void kernel_launch(void* const* d_in, const int* in_sizes, int n_in,
                              void* d_out, int out_size, void* d_ws, size_t ws_size,
                              hipStream_t stream) {
  const float* hs   = (const float*)d_in[0];
  const float* q_w  = (const float*)d_in[1];
  const float* q_b  = (const float*)d_in[2];
  const float* k_w  = (const float*)d_in[3];
  const float* k_b  = (const float*)d_in[4];
  const float* v_w  = (const float*)d_in[5];
  const float* v_b  = (const float*)d_in[6];
  const float* b_w  = (const float*)d_in[9];
  const float* b_b  = (const float*)d_in[10];
  const float* og_w = (const float*)d_in[11];
  const float* o_w  = (const float*)d_in[12];
  const float* o_b  = (const float*)d_in[13];

  const int M = 16384, K = 2048;
  const size_t MB64 = 67108864;         // one [M,2048] bf16 buffer

  // fast-path layout: qy|kn|gv|gate (contiguous, 256MiB) | hsb | wcat | owb
  //                   | beta | bias_cat
  const size_t OFF_HSB  = 4 * MB64;                 // 268435456
  const size_t OFF_WCAT = OFF_HSB + MB64;           // 335544320
  const size_t OFF_OWB  = OFF_WCAT + 33554432;      // 369098752
  const size_t OFF_BETA = OFF_OWB + 8388608;        // 377487360
  const size_t OFF_BIAS = OFF_BETA + 1048576;       // 378535936
  const size_t NEED     = OFF_BIAS + 32768;         // 378568704

  char* ws = (char*)d_ws;

  if (ws_size >= NEED) {
    unsigned short* qy   = (unsigned short*)ws;
    unsigned short* knb  = (unsigned short*)(ws + MB64);
    unsigned short* gv   = (unsigned short*)(ws + 2 * MB64);
    unsigned short* gate = (unsigned short*)(ws + 3 * MB64);
    unsigned short* hsb  = (unsigned short*)(ws + OFF_HSB);
    unsigned short* wcat = (unsigned short*)(ws + OFF_WCAT);
    unsigned short* owb  = (unsigned short*)(ws + OFF_OWB);
    float*          beta = (float*)(ws + OFF_BETA);
    float*          bias = (float*)(ws + OFF_BIAS);

    const int NW = 4194304;  // elems per 2048x2048 weight
    cvt_bf16<<<(M * K) / 2048, 256, 0, stream>>>(hs, hsb, M * K);
    cvt_bf16<<<NW / 2048, 256, 0, stream>>>(q_w,  wcat,          NW);
    cvt_bf16<<<NW / 2048, 256, 0, stream>>>(k_w,  wcat + NW,     NW);
    cvt_bf16<<<NW / 2048, 256, 0, stream>>>(v_w,  wcat + 2 * NW, NW);
    cvt_bf16<<<NW / 2048, 256, 0, stream>>>(og_w, wcat + 3 * NW, NW);
    cvt_bf16<<<NW / 2048, 256, 0, stream>>>(o_w,  owb,           NW);
    build_bias<<<32, 256, 0, stream>>>(q_b, k_b, v_b, bias);
    beta_kernel<<<M, 256, 0, stream>>>(hs, b_w, b_b, beta);

    gemm_async<0><<<dim3(64, 128), 256, 0, stream>>>(
        hsb, wcat, bias, beta, qy, M, 8192, K);

    attn_kernel<<<dim3(256, 16), 256, 0, stream>>>(qy, knb, gv, gate, qy);

    gemm_async<3><<<dim3(16, 128), 256, 0, stream>>>(
        qy, owb, o_b, nullptr, (float*)d_out, M, 2048, K);
  } else {
    // round-1 fallback (f32 pack staging), known-correct
    unsigned short* qy   = (unsigned short*)ws;
    unsigned short* knb  = (unsigned short*)(ws + MB64);
    unsigned short* gv   = (unsigned short*)(ws + 2 * MB64);
    unsigned short* gate = (unsigned short*)(ws + 3 * MB64);
    float*          beta = (float*)(ws + 4 * MB64);

    beta_kernel<<<M, 256, 0, stream>>>(hs, b_w, b_b, beta);
    dim3 gg(16, 128);
    gemm_bt<0, false><<<gg, 256, 0, stream>>>(hs, q_w, q_b, nullptr, qy, M, 2048, K);
    gemm_bt<0, false><<<gg, 256, 0, stream>>>(hs, k_w, k_b, nullptr, knb, M, 2048, K);
    gemm_bt<1, false><<<gg, 256, 0, stream>>>(hs, v_w, v_b, beta, gv, M, 2048, K);
    gemm_bt<2, false><<<gg, 256, 0, stream>>>(hs, og_w, nullptr, nullptr, gate, M, 2048, K);
    attn_kernel<<<dim3(256, 16), 256, 0, stream>>>(qy, knb, gv, gate, qy);
    gemm_bt<3, true><<<gg, 256, 0, stream>>>(qy, o_w, o_b, nullptr, (float*)d_out, M, 2048, K);
  }
}

// Round 3
// 1271.743 us; speedup vs baseline: 1.5438x; 1.1168x over previous
//
#include <hip/hip_runtime.h>

// ChunkwiseDeltaAttention (MI355X/gfx950) — round 3
// B=4 L=4096 H=2048 NH=16 D=128 C=64 -> M=16384, K=2048
//
// Fast path:
//   beta_kernel: beta = softplus(hs @ b_w^T + b_b), AND hs -> bf16 hsb (fused)
//   cvt: {q,k,v,og}_w -> bf16 wcat [8192,2048]; o_w -> owb
//   gemm_async<0,8192>: [qy|kn|gv|gate] = hsb @ wcat^T (+bias), fused epi
//   attn: l2norm in LDS, S=qk^T (MFMA), causal(=ones) mask, O=S gv, *gate
//   gemm_async<3,2048>: out = y @ o_w^T + o_b -> f32 d_out
//
// GEMM changes this round:
//   * XOR chunk swizzle on LDS (store contiguous per global_load_lds rule,
//     read chunk = quad ^ ((l16>>1)&3)) -> 8-way ds_read conflicts -> 2-way
//   * __launch_bounds__(256,4) + hardcoded K/N -> target 128 regs, 4 blk/CU

typedef __bf16 bf16x8 __attribute__((ext_vector_type(8)));
typedef float f32x4 __attribute__((ext_vector_type(4)));

typedef __attribute__((address_space(1))) const unsigned int g_u32;
typedef __attribute__((address_space(3))) unsigned int l_u32;

__device__ __forceinline__ void cp16(const unsigned short* g, unsigned short* l) {
  __builtin_amdgcn_global_load_lds((g_u32*)g, (l_u32*)l, 16, 0, 0);
}

__device__ __forceinline__ unsigned short f2bf(float x) {
  unsigned u = __builtin_bit_cast(unsigned, x);
  u += 0x7fffu + ((u >> 16) & 1u);          // RNE
  return (unsigned short)(u >> 16);
}
__device__ __forceinline__ float bf2f(unsigned short h) {
  return __builtin_bit_cast(float, (unsigned)h << 16);
}
__device__ __forceinline__ unsigned pk2(float a, float b) {
  return (unsigned)f2bf(a) | ((unsigned)f2bf(b) << 16);
}

// ------------------------------------------------------------- convert ----
__global__ __launch_bounds__(256) void cvt_bf16(const float* __restrict__ in,
                                                unsigned short* __restrict__ out,
                                                int n) {
  int i = (blockIdx.x * 256 + threadIdx.x) * 8;
  if (i >= n) return;
  float4 f0 = *(const float4*)(in + i);
  float4 f1 = *(const float4*)(in + i + 4);
  uint4 u;
  u.x = pk2(f0.x, f0.y); u.y = pk2(f0.z, f0.w);
  u.z = pk2(f1.x, f1.y); u.w = pk2(f1.z, f1.w);
  *(uint4*)(out + i) = u;
}

__global__ __launch_bounds__(256) void build_bias(
    const float* __restrict__ qb, const float* __restrict__ kb,
    const float* __restrict__ vb, float* __restrict__ bias_cat) {
  int i = blockIdx.x * 256 + threadIdx.x;   // 0..8191
  float v = 0.f;
  if (i < 2048) v = qb[i];
  else if (i < 4096) v = kb[i - 2048];
  else if (i < 6144) v = vb[i - 4096];
  bias_cat[i] = v;
}

// ------------------------------------------------- beta (+ hs->bf16) ------
__global__ __launch_bounds__(256) void beta_kernel(
    const float* __restrict__ hs, const float* __restrict__ bw,
    const float* __restrict__ bb, float* __restrict__ beta,
    unsigned short* __restrict__ hsb) {
  __shared__ float row[2048];
  __shared__ float part[16][17];
  const int m = blockIdx.x;
  const float* src = hs + (size_t)m * 2048;
  for (int i = threadIdx.x; i < 512; i += 256)
    ((float4*)row)[i] = ((const float4*)src)[i];
  __syncthreads();
  if (hsb) {  // fused f32->bf16 of this row
    int e = threadIdx.x * 8;
    uint4 u;
    u.x = pk2(row[e], row[e + 1]);     u.y = pk2(row[e + 2], row[e + 3]);
    u.z = pk2(row[e + 4], row[e + 5]); u.w = pk2(row[e + 6], row[e + 7]);
    *(uint4*)(hsb + (size_t)m * 2048 + e) = u;
  }
  const int h = threadIdx.x >> 4, j = threadIdx.x & 15;
  const float* w = bw + h * 2048;
  float s = 0.f;
  #pragma unroll 8
  for (int kk = 0; kk < 128; kk++) {
    int k = j + (kk << 4);
    s += row[k] * w[k];
  }
  part[h][j] = s;
  __syncthreads();
  if (threadIdx.x < 16) {
    int hh = threadIdx.x;
    float t = bb[hh];
    #pragma unroll
    for (int j2 = 0; j2 < 16; j2++) t += part[hh][j2];
    beta[(size_t)m * 16 + hh] = fmaxf(t, 0.f) + log1pf(__expf(-fabsf(t)));
  }
}

// ------------------------------------------------- GEMM (async staging) ----
// C[m,n] = sum_k A[m,k]*B[n,k], bf16. 128x128 tile, BK=32, XOR-swizzled LDS.
// EPI 0: fused qkvg epilogue, Cv = base of 4 contiguous [M,2048] bf16 bufs.
// EPI 3: f32 out [M,N], +bias.
template <int EPI, int N, int K>
__global__ __launch_bounds__(256, 4) void gemm_async(
    const unsigned short* __restrict__ A, const unsigned short* __restrict__ Bw,
    const float* __restrict__ bias, const float* __restrict__ beta,
    void* __restrict__ Cv) {
  __shared__ __align__(16) unsigned short As[128 * 32];
  __shared__ __align__(16) unsigned short Bs[128 * 32];
  const int tid = threadIdx.x;
  const int m0 = blockIdx.y * 128;
  const int n0 = blockIdx.x * 128;
  const int wid = tid >> 6, lane = tid & 63;
  const int wm = wid >> 1, wn = wid & 1;
  const int quad = lane >> 4, l16 = lane & 15;

  // stage: thread tid -> LDS bytes [tid*16, tid*16+16) (rows 0..63 of tile),
  //        +256 threads' worth for rows 64..127. Global col XOR-swizzled:
  //        physical chunk p of row r holds cols 8*(p ^ ((r>>1)&3)).
  const int srow = tid >> 2;
  const int scol = ((tid & 3) ^ ((tid >> 3) & 3)) << 3;
  const unsigned short* Ag0 = A + (size_t)(m0 + srow) * K + scol;
  const unsigned short* Ag1 = Ag0 + (size_t)64 * K;
  const unsigned short* Bg0 = Bw + (size_t)(n0 + srow) * K + scol;
  const unsigned short* Bg1 = Bg0 + (size_t)64 * K;
  unsigned short* la0 = &As[tid * 8];
  unsigned short* la1 = &As[(tid + 256) * 8];
  unsigned short* lb0 = &Bs[tid * 8];
  unsigned short* lb1 = &Bs[(tid + 256) * 8];

  // read-side swizzled chunk offset (elems); same for every row this lane
  // touches since rows differ by multiples of 16: ((row>>1)&3) == ((l16>>1)&3)
  const int pchunk = (quad ^ ((l16 >> 1) & 3)) << 3;

  f32x4 acc[4][4] = {};

  for (int kb = 0; kb < K; kb += 32) {
    cp16(Ag0 + kb, la0);
    cp16(Ag1 + kb, la1);
    cp16(Bg0 + kb, lb0);
    cp16(Bg1 + kb, lb1);
    __syncthreads();
    bf16x8 af[4], bfr[4];
    #pragma unroll
    for (int mi = 0; mi < 4; mi++)
      af[mi] = *(const bf16x8*)&As[(wm * 64 + mi * 16 + l16) * 32 + pchunk];
    #pragma unroll
    for (int ni = 0; ni < 4; ni++)
      bfr[ni] = *(const bf16x8*)&Bs[(wn * 64 + ni * 16 + l16) * 32 + pchunk];
    #pragma unroll
    for (int mi = 0; mi < 4; mi++)
      #pragma unroll
      for (int ni = 0; ni < 4; ni++)
        acc[mi][ni] = __builtin_amdgcn_mfma_f32_16x16x32_bf16(
            af[mi], bfr[ni], acc[mi][ni], 0, 0, 0);
    __syncthreads();
  }

  // epilogue; C/D layout: col=lane&15, row=quad*4+reg
  if (EPI == 0) {
    const int mode = n0 >> 11;              // 0:q 1:k 2:v 3:gate
    unsigned short* outp =
        (unsigned short*)Cv + (size_t)mode * ((size_t)16384 * 2048);
    const int head = (n0 >> 7) & 15;
    #pragma unroll
    for (int mi = 0; mi < 4; mi++) {
      #pragma unroll
      for (int r = 0; r < 4; r++) {
        const int row = m0 + wm * 64 + mi * 16 + quad * 4 + r;
        const float bsc = (mode == 2) ? beta[(size_t)row * 16 + head] : 1.f;
        #pragma unroll
        for (int ni = 0; ni < 4; ni++) {
          const int col = n0 + wn * 64 + ni * 16 + l16;
          float x = acc[mi][ni][r] + bias[col];
          if (mode == 2) x *= bsc;
          if (mode == 3) x = x / (1.f + __expf(-x));
          outp[(size_t)row * 2048 + (col & 2047)] = f2bf(x);
        }
      }
    }
  } else {
    #pragma unroll
    for (int mi = 0; mi < 4; mi++)
      #pragma unroll
      for (int r = 0; r < 4; r++) {
        const int row = m0 + wm * 64 + mi * 16 + quad * 4 + r;
        #pragma unroll
        for (int ni = 0; ni < 4; ni++) {
          const int col = n0 + wn * 64 + ni * 16 + l16;
          ((float*)Cv)[(size_t)row * N + col] = acc[mi][ni][r] + bias[col];
        }
      }
  }
}

// --------------------------------------------- fallback GEMM (round 1) ----
constexpr int GLDW = 40;
template <int EPI, bool ABF16>
__global__ __launch_bounds__(256) void gemm_bt(
    const void* __restrict__ Av, const float* __restrict__ Bw,
    const float* __restrict__ bias, const float* __restrict__ beta,
    void* __restrict__ Cv, int M, int N, int K) {
  __shared__ unsigned short As[128 * GLDW];
  __shared__ unsigned short Bs[128 * GLDW];
  const int tid = threadIdx.x;
  const int m0 = blockIdx.y * 128;
  const int n0 = blockIdx.x * 128;
  const int wid = tid >> 6, lane = tid & 63;
  const int wm = wid >> 1, wn = wid & 1;
  const int quad = lane >> 4, l16 = lane & 15;
  const int srow = tid >> 1, skh = (tid & 1) << 4;

  f32x4 acc[4][4] = {};
  const float* Bg = Bw + (size_t)(n0 + srow) * K + skh;

  for (int kb = 0; kb < K; kb += 32) {
    if (ABF16) {
      const unsigned short* Ag =
          (const unsigned short*)Av + (size_t)(m0 + srow) * K + kb + skh;
      uint4 u0 = ((const uint4*)Ag)[0];
      uint4 u1 = ((const uint4*)Ag)[1];
      uint4* d = (uint4*)&As[srow * GLDW + skh];
      d[0] = u0; d[1] = u1;
    } else {
      const float* Ag = (const float*)Av + (size_t)(m0 + srow) * K + kb + skh;
      float4 f0 = ((const float4*)Ag)[0];
      float4 f1 = ((const float4*)Ag)[1];
      float4 f2 = ((const float4*)Ag)[2];
      float4 f3 = ((const float4*)Ag)[3];
      unsigned* d = (unsigned*)&As[srow * GLDW + skh];
      d[0] = pk2(f0.x, f0.y); d[1] = pk2(f0.z, f0.w);
      d[2] = pk2(f1.x, f1.y); d[3] = pk2(f1.z, f1.w);
      d[4] = pk2(f2.x, f2.y); d[5] = pk2(f2.z, f2.w);
      d[6] = pk2(f3.x, f3.y); d[7] = pk2(f3.z, f3.w);
    }
    {
      const float* Bgk = Bg + kb;
      float4 f0 = ((const float4*)Bgk)[0];
      float4 f1 = ((const float4*)Bgk)[1];
      float4 f2 = ((const float4*)Bgk)[2];
      float4 f3 = ((const float4*)Bgk)[3];
      unsigned* d = (unsigned*)&Bs[srow * GLDW + skh];
      d[0] = pk2(f0.x, f0.y); d[1] = pk2(f0.z, f0.w);
      d[2] = pk2(f1.x, f1.y); d[3] = pk2(f1.z, f1.w);
      d[4] = pk2(f2.x, f2.y); d[5] = pk2(f2.z, f2.w);
      d[6] = pk2(f3.x, f3.y); d[7] = pk2(f3.z, f3.w);
    }
    __syncthreads();
    bf16x8 af[4], bfr[4];
    #pragma unroll
    for (int mi = 0; mi < 4; mi++)
      af[mi] = *(const bf16x8*)&As[(wm * 64 + mi * 16 + l16) * GLDW + (quad << 3)];
    #pragma unroll
    for (int ni = 0; ni < 4; ni++)
      bfr[ni] = *(const bf16x8*)&Bs[(wn * 64 + ni * 16 + l16) * GLDW + (quad << 3)];
    #pragma unroll
    for (int mi = 0; mi < 4; mi++)
      #pragma unroll
      for (int ni = 0; ni < 4; ni++)
        acc[mi][ni] = __builtin_amdgcn_mfma_f32_16x16x32_bf16(
            af[mi], bfr[ni], acc[mi][ni], 0, 0, 0);
    __syncthreads();
  }

  #pragma unroll
  for (int mi = 0; mi < 4; mi++) {
    #pragma unroll
    for (int r = 0; r < 4; r++) {
      const int row = m0 + wm * 64 + mi * 16 + quad * 4 + r;
      float bsc = 1.f;
      if (EPI == 1) bsc = beta[(size_t)row * 16 + blockIdx.x];
      #pragma unroll
      for (int ni = 0; ni < 4; ni++) {
        const int col = n0 + wn * 64 + ni * 16 + l16;
        float x = acc[mi][ni][r];
        if (EPI != 2) x += bias[col];
        if (EPI == 1) x *= bsc;
        if (EPI == 2) x = x / (1.f + __expf(-x));
        if (EPI == 3)
          ((float*)Cv)[(size_t)row * N + col] = x;
        else
          ((unsigned short*)Cv)[(size_t)row * N + col] = f2bf(x);
      }
    }
  }
}

// ----------------------------------------------------------- attention ----
constexpr int QK_LDW = 132;  // 264B = 66 banks = 2 mod 32: lanes spread
constexpr int GT_LDW = 66;   // 132B = 33 banks = 1 mod 32: write 16-way -> 4-way
constexpr int SS_LDW = 68;   // 136B = 34 banks = 2 mod 32

__global__ __launch_bounds__(256) void attn_kernel(
    const unsigned short* __restrict__ qn, const unsigned short* __restrict__ kn,
    const unsigned short* __restrict__ gvp, const unsigned short* __restrict__ gate,
    unsigned short* __restrict__ y) {
  __shared__ unsigned short qs[64 * QK_LDW];
  __shared__ unsigned short ks[64 * QK_LDW];
  __shared__ unsigned short gst[128 * GT_LDW];
  __shared__ unsigned short Ss[64 * SS_LDW];

  const int tid = threadIdx.x;
  const int m0 = blockIdx.x * 64;
  const int h = blockIdx.y;
  const size_t gbase = (size_t)m0 * 2048 + (size_t)h * 128;

  #pragma unroll
  for (int it = 0; it < 4; it++) {
    int e = tid + it * 256;
    int i = e >> 4;
    int c = (e & 15) << 3;
    size_t g = gbase + (size_t)i * 2048 + c;
    *(uint4*)&qs[i * QK_LDW + c] = *(const uint4*)&qn[g];
    *(uint4*)&ks[i * QK_LDW + c] = *(const uint4*)&kn[g];
    uint4 gvv = *(const uint4*)&gvp[g];
    unsigned short tmp[8];
    *(uint4*)tmp = gvv;
    #pragma unroll
    for (int t = 0; t < 8; t++) gst[(c + t) * GT_LDW + i] = tmp[t];
  }
  __syncthreads();

  {
    const int rr = tid >> 2;
    const int seg = (tid & 3) * 32;
    float ssq = 0.f, ssk = 0.f;
    #pragma unroll
    for (int k2 = 0; k2 < 32; k2 += 2) {
      unsigned uq = *(const unsigned*)&qs[rr * QK_LDW + seg + k2];
      unsigned uk = *(const unsigned*)&ks[rr * QK_LDW + seg + k2];
      float a = bf2f((unsigned short)(uq & 0xffff)), b = bf2f((unsigned short)(uq >> 16));
      float c2 = bf2f((unsigned short)(uk & 0xffff)), d2 = bf2f((unsigned short)(uk >> 16));
      ssq += a * a + b * b;
      ssk += c2 * c2 + d2 * d2;
    }
    ssq += __shfl_xor(ssq, 1); ssq += __shfl_xor(ssq, 2);
    ssk += __shfl_xor(ssk, 1); ssk += __shfl_xor(ssk, 2);
    float iq = rsqrtf(fmaxf(ssq, 1e-24f));
    float ik = rsqrtf(fmaxf(ssk, 1e-24f));
    #pragma unroll
    for (int k2 = 0; k2 < 32; k2 += 2) {
      unsigned uq = *(const unsigned*)&qs[rr * QK_LDW + seg + k2];
      unsigned uk = *(const unsigned*)&ks[rr * QK_LDW + seg + k2];
      float a = bf2f((unsigned short)(uq & 0xffff)), b = bf2f((unsigned short)(uq >> 16));
      float c2 = bf2f((unsigned short)(uk & 0xffff)), d2 = bf2f((unsigned short)(uk >> 16));
      *(unsigned*)&qs[rr * QK_LDW + seg + k2] = pk2(a * iq, b * iq);
      *(unsigned*)&ks[rr * QK_LDW + seg + k2] = pk2(c2 * ik, d2 * ik);
    }
  }
  __syncthreads();

  const int w = tid >> 6;
  const int lane = tid & 63;
  const int quad = lane >> 4, l16 = lane & 15;

  {
    f32x4 acc[4] = {};
    #pragma unroll
    for (int kst = 0; kst < 4; kst++) {
      bf16x8 a = *(const bf16x8*)&qs[(w * 16 + l16) * QK_LDW + kst * 32 + (quad << 3)];
      #pragma unroll
      for (int ni = 0; ni < 4; ni++) {
        bf16x8 b = *(const bf16x8*)&ks[(ni * 16 + l16) * QK_LDW + kst * 32 + (quad << 3)];
        acc[ni] = __builtin_amdgcn_mfma_f32_16x16x32_bf16(a, b, acc[ni], 0, 0, 0);
      }
    }
    #pragma unroll
    for (int ni = 0; ni < 4; ni++)
      #pragma unroll
      for (int r = 0; r < 4; r++) {
        int row = w * 16 + quad * 4 + r;
        int col = ni * 16 + l16;
        float val = (col <= row) ? acc[ni][r] : 0.f;
        Ss[row * SS_LDW + col] = f2bf(val);
      }
  }
  __syncthreads();

  {
    f32x4 acc[8] = {};
    #pragma unroll
    for (int kst = 0; kst < 2; kst++) {
      bf16x8 a = *(const bf16x8*)&Ss[(w * 16 + l16) * SS_LDW + kst * 32 + (quad << 3)];
      #pragma unroll
      for (int nd = 0; nd < 8; nd++) {
        bf16x8 b = *(const bf16x8*)&gst[(nd * 16 + l16) * GT_LDW + kst * 32 + (quad << 3)];
        acc[nd] = __builtin_amdgcn_mfma_f32_16x16x32_bf16(a, b, acc[nd], 0, 0, 0);
      }
    }
    #pragma unroll
    for (int nd = 0; nd < 8; nd++)
      #pragma unroll
      for (int r = 0; r < 4; r++) {
        int row = w * 16 + quad * 4 + r;
        int col = nd * 16 + l16;
        size_t g = gbase + (size_t)row * 2048 + col;
        float gt = bf2f(gate[g]);
        y[g] = f2bf(acc[nd][r] * gt);
      }
  }
}

// --------------------------------------------------------------- launch ---
extern "C" void kernel_launch(void* const* d_in, const int* in_sizes, int n_in,
                              void* d_out, int out_size, void* d_ws, size_t ws_size,
                              hipStream_t stream) {
  const float* hs   = (const float*)d_in[0];
  const float* q_w  = (const float*)d_in[1];
  const float* q_b  = (const float*)d_in[2];
  const float* k_w  = (const float*)d_in[3];
  const float* k_b  = (const float*)d_in[4];
  const float* v_w  = (const float*)d_in[5];
  const float* v_b  = (const float*)d_in[6];
  const float* b_w  = (const float*)d_in[9];
  const float* b_b  = (const float*)d_in[10];
  const float* og_w = (const float*)d_in[11];
  const float* o_w  = (const float*)d_in[12];
  const float* o_b  = (const float*)d_in[13];

  const int M = 16384, K = 2048;
  const size_t MB64 = 67108864;         // one [M,2048] bf16 buffer

  const size_t OFF_HSB  = 4 * MB64;
  const size_t OFF_WCAT = OFF_HSB + MB64;
  const size_t OFF_OWB  = OFF_WCAT + 33554432;
  const size_t OFF_BETA = OFF_OWB + 8388608;
  const size_t OFF_BIAS = OFF_BETA + 1048576;
  const size_t NEED     = OFF_BIAS + 32768;

  char* ws = (char*)d_ws;

  if (ws_size >= NEED) {
    unsigned short* qy   = (unsigned short*)ws;
    unsigned short* knb  = (unsigned short*)(ws + MB64);
    unsigned short* gv   = (unsigned short*)(ws + 2 * MB64);
    unsigned short* gate = (unsigned short*)(ws + 3 * MB64);
    unsigned short* hsb  = (unsigned short*)(ws + OFF_HSB);
    unsigned short* wcat = (unsigned short*)(ws + OFF_WCAT);
    unsigned short* owb  = (unsigned short*)(ws + OFF_OWB);
    float*          beta = (float*)(ws + OFF_BETA);
    float*          bias = (float*)(ws + OFF_BIAS);

    const int NW = 4194304;  // elems per 2048x2048 weight
    cvt_bf16<<<NW / 2048, 256, 0, stream>>>(q_w,  wcat,          NW);
    cvt_bf16<<<NW / 2048, 256, 0, stream>>>(k_w,  wcat + NW,     NW);
    cvt_bf16<<<NW / 2048, 256, 0, stream>>>(v_w,  wcat + 2 * NW, NW);
    cvt_bf16<<<NW / 2048, 256, 0, stream>>>(og_w, wcat + 3 * NW, NW);
    cvt_bf16<<<NW / 2048, 256, 0, stream>>>(o_w,  owb,           NW);
    build_bias<<<32, 256, 0, stream>>>(q_b, k_b, v_b, bias);
    beta_kernel<<<M, 256, 0, stream>>>(hs, b_w, b_b, beta, hsb);  // + hs->bf16

    gemm_async<0, 8192, 2048><<<dim3(64, 128), 256, 0, stream>>>(
        hsb, wcat, bias, beta, qy);

    attn_kernel<<<dim3(256, 16), 256, 0, stream>>>(qy, knb, gv, gate, qy);

    gemm_async<3, 2048, 2048><<<dim3(16, 128), 256, 0, stream>>>(
        qy, owb, o_b, nullptr, (float*)d_out);
  } else {
    // round-1 fallback (f32 pack staging), known-correct
    unsigned short* qy   = (unsigned short*)ws;
    unsigned short* knb  = (unsigned short*)(ws + MB64);
    unsigned short* gv   = (unsigned short*)(ws + 2 * MB64);
    unsigned short* gate = (unsigned short*)(ws + 3 * MB64);
    float*          beta = (float*)(ws + 4 * MB64);

    beta_kernel<<<M, 256, 0, stream>>>(hs, b_w, b_b, beta, nullptr);
    dim3 gg(16, 128);
    gemm_bt<0, false><<<gg, 256, 0, stream>>>(hs, q_w, q_b, nullptr, qy, M, 2048, K);
    gemm_bt<0, false><<<gg, 256, 0, stream>>>(hs, k_w, k_b, nullptr, knb, M, 2048, K);
    gemm_bt<1, false><<<gg, 256, 0, stream>>>(hs, v_w, v_b, beta, gv, M, 2048, K);
    gemm_bt<2, false><<<gg, 256, 0, stream>>>(hs, og_w, nullptr, nullptr, gate, M, 2048, K);
    attn_kernel<<<dim3(256, 16), 256, 0, stream>>>(qy, knb, gv, gate, qy);
    gemm_bt<3, true><<<gg, 256, 0, stream>>>(qy, o_w, o_b, nullptr, (float*)d_out, M, 2048, K);
  }
}